// Round 1
// baseline (862.578 us; speedup 1.0000x reference)
//
#include <hip/hip_runtime.h>

// Problem constants (from reference): B=8, S=2048, T=512, HD=4096, fp32.
#define B_DIM 8
#define S_DIM 2048          // 2^11
#define T_DIM 512
#define HD_DIM 4096         // 2^12
#define HDV 1024            // HD/4 float4 per row, 2^10

// ---------------------------------------------------------------------------
// Kernel 1: build inverse map  map[s] = t if input_pos[t]==s else -1.
// Single block of 1024 threads: init all 2048 entries, sync, scatter 512.
// Workspace is poisoned to 0xAA before every call, so we must init ourselves.
// ---------------------------------------------------------------------------
__global__ void build_map_kernel(const int* __restrict__ input_pos,
                                 int* __restrict__ map) {
    int tid = threadIdx.x;                 // 0..1023
    map[tid] = -1;
    map[tid + 1024] = -1;
    __syncthreads();
    if (tid < T_DIM) {
        int p = input_pos[tid];
        if (p >= 0 && p < S_DIM) map[p] = tid;
    }
}

// ---------------------------------------------------------------------------
// Kernel 2: one float4 per thread over BOTH output tensors (k then v).
// Row s with map[s]>=0 is sourced from val; otherwise from cache.
// Each 4096-float row = 1024 float4 = 16 waves -> branches are wave-uniform.
// ---------------------------------------------------------------------------
__global__ void kv_update_kernel(const float4* __restrict__ k_cache,
                                 const float4* __restrict__ v_cache,
                                 const float4* __restrict__ k_val,
                                 const float4* __restrict__ v_val,
                                 const int* __restrict__ map,
                                 float4* __restrict__ out) {
    const unsigned per_tensor = (unsigned)B_DIM * S_DIM * HDV;   // 2^24
    unsigned idx = blockIdx.x * blockDim.x + threadIdx.x;        // < 2^25

    bool is_v = idx >= per_tensor;                // uniform per block
    unsigned e = is_v ? (idx - per_tensor) : idx;

    unsigned col = e & (HDV - 1);                 // bits 0..9
    unsigned s   = (e >> 10) & (S_DIM - 1);       // bits 10..20
    unsigned b   = e >> 21;                       // bits 21..23

    int t = map[s];                               // 8 KiB array, L1-resident
    const float4* __restrict__ cache = is_v ? v_cache : k_cache;
    const float4* __restrict__ val   = is_v ? v_val   : k_val;

    float4 r;
    if (t >= 0) {
        r = val[((unsigned)b * T_DIM + (unsigned)t) * HDV + col];
    } else {
        r = cache[e];
    }
    out[idx] = r;
}

// ---------------------------------------------------------------------------
// Fallback (only if ws too small): plain copy caches -> out, then scatter vals.
// ---------------------------------------------------------------------------
__global__ void copy_kernel(const float4* __restrict__ k_cache,
                            const float4* __restrict__ v_cache,
                            float4* __restrict__ out) {
    const unsigned per_tensor = (unsigned)B_DIM * S_DIM * HDV;
    unsigned idx = blockIdx.x * blockDim.x + threadIdx.x;
    out[idx] = (idx >= per_tensor) ? v_cache[idx - per_tensor] : k_cache[idx];
}

__global__ void scatter_kernel(const float4* __restrict__ k_val,
                               const float4* __restrict__ v_val,
                               const int* __restrict__ input_pos,
                               float4* __restrict__ out) {
    const unsigned per_val = (unsigned)B_DIM * T_DIM * HDV;      // 2^22
    const unsigned per_tensor = (unsigned)B_DIM * S_DIM * HDV;   // 2^24
    unsigned idx = blockIdx.x * blockDim.x + threadIdx.x;        // < 2^23
    bool is_v = idx >= per_val;
    unsigned e = is_v ? (idx - per_val) : idx;
    unsigned col = e & (HDV - 1);
    unsigned t   = (e >> 10) & (T_DIM - 1);
    unsigned b   = e >> 19;
    int p = input_pos[t];
    float4 r = is_v ? v_val[e] : k_val[e];
    unsigned o = ((unsigned)b * S_DIM + (unsigned)p) * HDV + col
               + (is_v ? per_tensor : 0u);
    out[o] = r;
}

extern "C" void kernel_launch(void* const* d_in, const int* in_sizes, int n_in,
                              void* d_out, int out_size, void* d_ws, size_t ws_size,
                              hipStream_t stream) {
    const float4* k_cache  = (const float4*)d_in[0];
    const float4* v_cache  = (const float4*)d_in[1];
    const float4* k_val    = (const float4*)d_in[2];
    const float4* v_val    = (const float4*)d_in[3];
    const int*    input_pos = (const int*)d_in[4];
    float4* out = (float4*)d_out;

    const unsigned per_tensor = (unsigned)B_DIM * S_DIM * HDV;   // 2^24 float4
    const unsigned total = 2u * per_tensor;                      // 2^25 float4

    if (ws_size >= S_DIM * sizeof(int)) {
        int* map = (int*)d_ws;
        build_map_kernel<<<1, 1024, 0, stream>>>(input_pos, map);
        kv_update_kernel<<<total / 256, 256, 0, stream>>>(
            k_cache, v_cache, k_val, v_val, map, out);
    } else {
        copy_kernel<<<total / 256, 256, 0, stream>>>(k_cache, v_cache, out);
        const unsigned sc_total = 2u * (unsigned)B_DIM * T_DIM * HDV; // 2^23
        scatter_kernel<<<sc_total / 256, 256, 0, stream>>>(
            k_val, v_val, input_pos, out);
    }
}

// Round 3
// 859.760 us; speedup vs baseline: 1.0033x; 1.0033x over previous
//
#include <hip/hip_runtime.h>

// Problem constants (from reference): B=8, S=2048, T=512, HD=4096, fp32.
#define B_DIM 8
#define S_DIM 2048          // 2^11 rows per batch
#define T_DIM 512           // update rows
#define HDV   1024          // HD/4 = float4 per row, 2^10

// Native clang vector type — required by __builtin_nontemporal_load/store
// (HIP's float4 is a struct and is rejected).
typedef float floatx4 __attribute__((ext_vector_type(4)));

// ---------------------------------------------------------------------------
// Single fused kernel. One thread handles the SAME (b, s, col) float4 slot in
// both the K and V output tensors (32 B read + 32 B write per thread).
//
// s is block-uniform: blockDim=256 float4 = quarter of a 1024-float4 row,
// and rows are 256-aligned in the flat index. So each wave does ONE search
// of input_pos (2 KiB, L1/L2-resident after warmup): 512 entries / 64 lanes
// = 8 per-lane loads + __ballot. All lanes agree on t; branch is uniform.
//
// All bulk traffic is single-use streaming -> nontemporal loads/stores.
// ---------------------------------------------------------------------------
__global__ void __launch_bounds__(256)
kv_update_kernel(const floatx4* __restrict__ k_cache,
                 const floatx4* __restrict__ v_cache,
                 const floatx4* __restrict__ k_val,
                 const floatx4* __restrict__ v_val,
                 const int* __restrict__ input_pos,
                 floatx4* __restrict__ out) {
    const unsigned per_tensor = (unsigned)B_DIM * S_DIM * HDV;   // 2^24 float4
    unsigned e = blockIdx.x * blockDim.x + threadIdx.x;          // < 2^24

    unsigned col = e & (HDV - 1);                 // bits 0..9
    unsigned s   = (e >> 10) & (S_DIM - 1);       // bits 10..20 (block-uniform)
    unsigned b   = e >> 21;                       // bits 21..23

    // Wave-level inverse lookup: t s.t. input_pos[t] == s, else -1.
    int lane = threadIdx.x & 63;
    int t = -1;
#pragma unroll
    for (int i = 0; i < T_DIM / 64; ++i) {
        int p = input_pos[i * 64 + lane];         // cached, NOT nontemporal
        unsigned long long m = __ballot(p == (int)s);
        if (m) t = i * 64 + (__ffsll((long long)m) - 1);
    }

    floatx4 rk, rv;
    if (t >= 0) {
        unsigned vi = (b * (unsigned)T_DIM + (unsigned)t) * HDV + col;
        rk = __builtin_nontemporal_load(k_val + vi);
        rv = __builtin_nontemporal_load(v_val + vi);
    } else {
        rk = __builtin_nontemporal_load(k_cache + e);
        rv = __builtin_nontemporal_load(v_cache + e);
    }
    __builtin_nontemporal_store(rk, out + e);
    __builtin_nontemporal_store(rv, out + per_tensor + e);
}

extern "C" void kernel_launch(void* const* d_in, const int* in_sizes, int n_in,
                              void* d_out, int out_size, void* d_ws, size_t ws_size,
                              hipStream_t stream) {
    const floatx4* k_cache   = (const floatx4*)d_in[0];
    const floatx4* v_cache   = (const floatx4*)d_in[1];
    const floatx4* k_val     = (const floatx4*)d_in[2];
    const floatx4* v_val     = (const floatx4*)d_in[3];
    const int*     input_pos = (const int*)d_in[4];
    floatx4* out = (floatx4*)d_out;

    const unsigned per_tensor = (unsigned)B_DIM * S_DIM * HDV;   // 2^24 float4
    kv_update_kernel<<<per_tensor / 256, 256, 0, stream>>>(
        k_cache, v_cache, k_val, v_val, input_pos, out);
}

// Round 4
// 857.541 us; speedup vs baseline: 1.0059x; 1.0026x over previous
//
#include <hip/hip_runtime.h>

// Problem constants (from reference): B=8, S=2048, T=512, HD=4096, fp32.
#define B_DIM 8
#define S_DIM 2048          // 2^11 rows per batch
#define T_DIM 512           // update rows
#define HDV   1024          // HD/4 = float4 per row, 2^10

// Native clang vector type — required by __builtin_nontemporal_load/store
// (HIP's float4 is a struct and is rejected).
typedef float floatx4 __attribute__((ext_vector_type(4)));

// ---------------------------------------------------------------------------
// One block per (b, s) row; the block copies that row for BOTH K and V.
// Row = 1024 float4; 256 threads x 4 float4 per tensor (col = tid + 256*j,
// fully coalesced). Each thread does the input_pos search ONCE (8 iters of
// load+ballot over the 2 KiB L1-resident index array), amortized over 256 B
// of payload, then issues all 8 nontemporal loads back-to-back (8 outstanding
// 16 B loads -> high MLP) before the 8 nontemporal stores.
//
// Duplicate positions: reference .set takes the LAST occurrence -> scan keeps
// the highest t (63 - clz within a group; later groups overwrite).
// ---------------------------------------------------------------------------
__global__ void __launch_bounds__(256)
kv_update_kernel(const floatx4* __restrict__ k_cache,
                 const floatx4* __restrict__ v_cache,
                 const floatx4* __restrict__ k_val,
                 const floatx4* __restrict__ v_val,
                 const int* __restrict__ input_pos,
                 floatx4* __restrict__ out) {
    const unsigned per_tensor = (unsigned)B_DIM * S_DIM * HDV;   // 2^24 float4

    unsigned r = blockIdx.x;                      // (b,s) row id, < B*S
    unsigned s = r & (S_DIM - 1);
    unsigned b = r >> 11;

    // Wave-level inverse lookup: last t with input_pos[t] == s, else -1.
    int lane = threadIdx.x & 63;
    int t = -1;
#pragma unroll
    for (int i = 0; i < T_DIM / 64; ++i) {
        int p = input_pos[i * 64 + lane];          // cached, NOT nontemporal
        unsigned long long m = __ballot(p == (int)s);
        if (m) t = i * 64 + (63 - __clzll((long long)m));
    }

    const floatx4* __restrict__ srcK;
    const floatx4* __restrict__ srcV;
    unsigned sbase;
    if (t >= 0) {
        sbase = (b * (unsigned)T_DIM + (unsigned)t) * HDV;
        srcK = k_val;  srcV = v_val;
    } else {
        sbase = (b * (unsigned)S_DIM + s) * HDV;
        srcK = k_cache; srcV = v_cache;
    }
    unsigned obase = (b * (unsigned)S_DIM + s) * HDV + threadIdx.x;
    sbase += threadIdx.x;

    // 8 independent loads in flight, then 8 stores.
    floatx4 k0 = __builtin_nontemporal_load(srcK + sbase + 0 * 256);
    floatx4 k1 = __builtin_nontemporal_load(srcK + sbase + 1 * 256);
    floatx4 k2 = __builtin_nontemporal_load(srcK + sbase + 2 * 256);
    floatx4 k3 = __builtin_nontemporal_load(srcK + sbase + 3 * 256);
    floatx4 v0 = __builtin_nontemporal_load(srcV + sbase + 0 * 256);
    floatx4 v1 = __builtin_nontemporal_load(srcV + sbase + 1 * 256);
    floatx4 v2 = __builtin_nontemporal_load(srcV + sbase + 2 * 256);
    floatx4 v3 = __builtin_nontemporal_load(srcV + sbase + 3 * 256);

    __builtin_nontemporal_store(k0, out + obase + 0 * 256);
    __builtin_nontemporal_store(k1, out + obase + 1 * 256);
    __builtin_nontemporal_store(k2, out + obase + 2 * 256);
    __builtin_nontemporal_store(k3, out + obase + 3 * 256);
    __builtin_nontemporal_store(v0, out + per_tensor + obase + 0 * 256);
    __builtin_nontemporal_store(v1, out + per_tensor + obase + 1 * 256);
    __builtin_nontemporal_store(v2, out + per_tensor + obase + 2 * 256);
    __builtin_nontemporal_store(v3, out + per_tensor + obase + 3 * 256);
}

extern "C" void kernel_launch(void* const* d_in, const int* in_sizes, int n_in,
                              void* d_out, int out_size, void* d_ws, size_t ws_size,
                              hipStream_t stream) {
    const floatx4* k_cache   = (const floatx4*)d_in[0];
    const floatx4* v_cache   = (const floatx4*)d_in[1];
    const floatx4* k_val     = (const floatx4*)d_in[2];
    const floatx4* v_val     = (const floatx4*)d_in[3];
    const int*     input_pos = (const int*)d_in[4];
    floatx4* out = (floatx4*)d_out;

    kv_update_kernel<<<B_DIM * S_DIM, 256, 0, stream>>>(
        k_cache, v_cache, k_val, v_val, input_pos, out);
}